// Round 16
// baseline (455.383 us; speedup 1.0000x reference)
//
#include <hip/hip_runtime.h>
#include <math.h>

#define BB 16
#define NN 512
#define TT 32
#define CC 128
#define RR 32
#define DD 64

// numpy npyv(AVX512) einsum contig-two dot emulation (FROZEN CONTRACT):
// 16-lane FMA accumulator over ascending 16-blocks + _mm512_reduce_add_ps tree.
__device__ __forceinline__ float dot_np16(const float* __restrict__ a,
                                          const float* __restrict__ b, int n) {
    float lane[16];
#pragma unroll
    for (int l = 0; l < 16; ++l) lane[l] = 0.0f;
    for (int i = 0; i < n; i += 16) {
#pragma unroll
        for (int l = 0; l < 16; ++l)
            lane[l] = __fmaf_rn(a[i + l], b[i + l], lane[l]);
    }
    float m[8], p[4];
#pragma unroll
    for (int i = 0; i < 8; ++i) m[i] = __fadd_rn(lane[i], lane[i + 8]);
#pragma unroll
    for (int i = 0; i < 4; ++i) p[i] = __fadd_rn(m[i], m[i + 4]);
    float q0 = __fadd_rn(p[0], p[2]);
    float q1 = __fadd_rn(p[1], p[3]);
    return __fadd_rn(q0, q1);
}

__device__ __forceinline__ float reduce_np16(const float (&lane)[16]) {
    float m[8], p[4];
#pragma unroll
    for (int i = 0; i < 8; ++i) m[i] = __fadd_rn(lane[i], lane[i + 8]);
#pragma unroll
    for (int i = 0; i < 4; ++i) p[i] = __fadd_rn(m[i], m[i + 4]);
    float q0 = __fadd_rn(p[0], p[2]);
    float q1 = __fadd_rn(p[1], p[3]);
    return __fadd_rn(q0, q1);
}

#define XS2 132   // mult of 4: 16B-aligned rows; b128 row-varying reads bank-balanced (r11/r12: 0 conflicts)

// ------------- Kernel 1: per-(b,n) pipeline -> Q,K (fp32-faithful) -----------
// 512 threads = 8 waves. z_ta: wave w owns rows {q,q+8,q+16,q+24} with
// q = readfirstlane(w) -> Ws reads are WAVE-UNIFORM scalar loads (SMEM pipe,
// no VGPRs, no LDS). Lanes duplicate across halves (t = lane&31). 2 passes of
// 2 rows: acc 32 VGPR, xv read once per chunk as b128 and reused ->
// 64 ds_read_b128/thread = 512/block (r12 had 1024/block at ~12cyc each).
__global__ __launch_bounds__(512) void k1(const float* __restrict__ x,
        const float* __restrict__ Ws, const float* __restrict__ Wphi,
        const float* __restrict__ b_phi, const float* __restrict__ Wmu,
        const float* __restrict__ b_mu, const float* __restrict__ WQ,
        const float* __restrict__ WK,
        float* __restrict__ gQ, float* __restrict__ gK)
{
    __shared__ float Xs[TT * XS2];    // 16.9 KB  (X, later X_hat in place)
    __shared__ float zta[TT * 33];    // 4.2 KB
    __shared__ float xc[CC];          // avg, later X_c
    __shared__ float wsh[CC];
    __shared__ float zca[RR];
    __shared__ float lg[TT];
    __shared__ float alpha[TT];

    const int tid = threadIdx.x;      // 0..511
    const int bn = blockIdx.x;
    const float* xb = x + (long long)bn * (TT * CC);

    // float4 staging of X (coalesced global, aligned LDS)
#pragma unroll
    for (int k = 0; k < 2; ++k) {
        int idx = tid + (k << 9);          // float4 idx 0..1023
        int t  = idx >> 5;
        int c4 = (idx & 31) << 2;
        *(float4*)&Xs[t * XS2 + c4] = ((const float4*)xb)[idx];
    }
    __syncthreads();

    // avg = np.mean over t (pairwise 8-acc), /32
    if (tid < CC) {
        float r[8];
#pragma unroll
        for (int j = 0; j < 8; ++j) r[j] = Xs[j * XS2 + tid];
#pragma unroll
        for (int i = 8; i < 32; i += 8)
#pragma unroll
            for (int j = 0; j < 8; ++j) r[j] = __fadd_rn(r[j], Xs[(i + j) * XS2 + tid]);
        float s = __fadd_rn(__fadd_rn(__fadd_rn(r[0], r[1]), __fadd_rn(r[2], r[3])),
                            __fadd_rn(__fadd_rn(r[4], r[5]), __fadd_rn(r[6], r[7])));
        xc[tid] = s / 32.0f;               // xc holds avg
    }
    __syncthreads();

    // z_ca = relu(avg . Ws[r,:]) -- Ws from global (r13/r15-verified)
    if (tid < RR) {
        const float* wr = Ws + tid * CC;
        float lane[16];
#pragma unroll
        for (int l = 0; l < 16; ++l) lane[l] = 0.0f;
#pragma unroll
        for (int c = 0; c < CC; c += 4) {
            float4 av = *(const float4*)&xc[c];
            float4 wv = *(const float4*)&wr[c];
            lane[(c & 15) + 0] = __fmaf_rn(av.x, wv.x, lane[(c & 15) + 0]);
            lane[(c & 15) + 1] = __fmaf_rn(av.y, wv.y, lane[(c & 15) + 1]);
            lane[(c & 15) + 2] = __fmaf_rn(av.z, wv.z, lane[(c & 15) + 2]);
            lane[(c & 15) + 3] = __fmaf_rn(av.w, wv.w, lane[(c & 15) + 3]);
        }
        zca[tid] = fmaxf(reduce_np16(lane), 0.0f);
    }
    __syncthreads();

    // w = sigmoid(zca . Wphi[c,:] + b_phi)
    if (tid < CC) {
        float t = __fadd_rn(dot_np16(zca, Wphi + tid * RR, RR), b_phi[tid]);
        wsh[tid] = 1.0f / (1.0f + expf(-t));
    }
    __syncthreads();

    // X_hat in place: Xs <- __fmul_rn(Xs, wsh)
#pragma unroll
    for (int k = 0; k < 8; ++k) {
        int i = tid + (k << 9);
        int t = i >> 7, c = i & 127;
        Xs[t * XS2 + c] = __fmul_rn(Xs[t * XS2 + c], wsh[c]);
    }
    __syncthreads();

    // z_ta = relu(X_hat . Ws^T): wave-uniform rows, SGPR Ws, b128 xv reuse.
    {
        const int lane = tid & 63;
        const int q = __builtin_amdgcn_readfirstlane(tid >> 6);  // wave id, uniform
        const int t = lane & 31;
        const float* xr = &Xs[t * XS2];
#pragma unroll
        for (int pass = 0; pass < 2; ++pass) {
            const float* w0 = Ws + (q + 16 * pass) * CC;       // rows q+16p, q+8+16p
            const float* w1 = Ws + (q + 8 + 16 * pass) * CC;
            float l0[16], l1[16];
#pragma unroll
            for (int l = 0; l < 16; ++l) { l0[l] = 0.0f; l1[l] = 0.0f; }
#pragma unroll
            for (int m = 0; m < 8; ++m) {
                float xf[16];
                *(float4*)(xf + 0)  = *(const float4*)&xr[m * 16 + 0];
                *(float4*)(xf + 4)  = *(const float4*)&xr[m * 16 + 4];
                *(float4*)(xf + 8)  = *(const float4*)&xr[m * 16 + 8];
                *(float4*)(xf + 12) = *(const float4*)&xr[m * 16 + 12];
#pragma unroll
                for (int e = 0; e < 16; ++e) {
                    l0[e] = __fmaf_rn(xf[e], w0[m * 16 + e], l0[e]);  // uniform -> SGPR
                    l1[e] = __fmaf_rn(xf[e], w1[m * 16 + e], l1[e]);
                }
            }
            if ((lane >> 5) == 0) {
                zta[t * 33 + q + 16 * pass]     = fmaxf(reduce_np16(l0), 0.0f);
                zta[t * 33 + q + 8 + 16 * pass] = fmaxf(reduce_np16(l1), 0.0f);
            }
        }
    }
    __syncthreads();

    // logits
    if (tid < TT) lg[tid] = __fadd_rn(dot_np16(&zta[tid * 33], Wmu, RR), b_mu[0]);
    __syncthreads();

    // softmax over t (max exact; pairwise 8-acc sum like np)
    if (tid == 0) {
        float m = lg[0];
        for (int t = 1; t < TT; ++t) m = fmaxf(m, lg[t]);
        float e[TT];
        for (int t = 0; t < TT; ++t) e[t] = expf(__fsub_rn(lg[t], m));
        float r[8];
#pragma unroll
        for (int j = 0; j < 8; ++j) r[j] = e[j];
#pragma unroll
        for (int i = 8; i < 32; i += 8)
#pragma unroll
            for (int j = 0; j < 8; ++j) r[j] = __fadd_rn(r[j], e[i + j]);
        float s = __fadd_rn(__fadd_rn(__fadd_rn(r[0], r[1]), __fadd_rn(r[2], r[3])),
                            __fadd_rn(__fadd_rn(r[4], r[5]), __fadd_rn(r[6], r[7])));
        for (int t = 0; t < TT; ++t) alpha[t] = e[t] / s;
    }
    __syncthreads();

    // X_c = einsum('t,tc->c', alpha, X_hat): sequential FMA on in-place X_hat
    if (tid < CC) {
        float s = 0.0f;
        for (int t = 0; t < TT; ++t)
            s = __fmaf_rn(alpha[t], Xs[t * XS2 + tid], s);
        xc[tid] = s;
    }
    __syncthreads();

    // Q, K projections
    if (tid < 128) {
        int isK = tid >> 6, d = tid & 63;
        const float* Wr = (isK ? WK : WQ) + d * CC;
        float s = dot_np16(xc, Wr, CC);
        if (isK) gK[bn * DD + d] = s;
        else     gQ[bn * DD + d] = s;
    }
}

// ------------- Kernel 2: E rows (np-order fp32) + sigmoid-domain top-8 -------
__device__ __forceinline__ void cxf(float& a, float& b) {
    float mx = fmaxf(a, b), mn = fminf(a, b);
    a = mx; b = mn;
}

#define KS 68   // Kch row stride: mult of 4 (aligned b128), uniform banks

__global__ __launch_bounds__(256) void k2f(const float* __restrict__ gQ,
                                           const float* __restrict__ gK,
                                           float* __restrict__ out)
{
    __shared__ float Qs[16][64];
    __shared__ float Kch[64 * KS];

    const int tid = threadIdx.x;
    const int gid = blockIdx.x;
    const int dir = gid & 1;
    const int b   = (gid >> 1) & 15;
    const int grp = gid >> 5;                 // 0..31
    const int row_base = grp << 4;

    const float* Qrow = dir ? gK : gQ;        // backward: rows come from K
    const float* Mat  = dir ? gQ : gK;
    float* outp = out + (long long)dir * BB * NN * NN;

    {   // float4 staging of the 16 query rows
        int row = tid >> 4, c4 = (tid & 15) << 2;
        *(float4*)&Qs[row][c4] =
            ((const float4*)Qrow)[(long long)(b * NN + row_base + row) * 16 + (tid & 15)];
    }

    const int l = tid & 63, w = tid >> 6, wrow = w << 2;
    float A[4][8];

#pragma unroll
    for (int j = 0; j < 8; ++j) {             // 8 column chunks of 64
        __syncthreads();                       // covers Qs on j==0, Kch reuse after
#pragma unroll
        for (int k = 0; k < 4; ++k) {          // float4 staging of 64x64 chunk
            int idx = tid + (k << 8);          // 0..1023
            int row = idx >> 4, c4 = (idx & 15) << 2;
            *(float4*)&Kch[row * KS + c4] =
                ((const float4*)Mat)[(long long)(b * NN + (j << 6) + row) * 16 + (idx & 15)];
        }
        __syncthreads();
#pragma unroll
        for (int r = 0; r < 4; ++r) {
            const float* qa = Qs[wrow + r];
            const float* kb = &Kch[l * KS];
            float lane[16];
#pragma unroll
            for (int ll = 0; ll < 16; ++ll) lane[ll] = 0.0f;
#pragma unroll
            for (int c = 0; c < DD; c += 4) {
                float4 qv = *(const float4*)&qa[c];
                float4 kv = *(const float4*)&kb[c];
                lane[(c & 15) + 0] = __fmaf_rn(qv.x, kv.x, lane[(c & 15) + 0]);
                lane[(c & 15) + 1] = __fmaf_rn(qv.y, kv.y, lane[(c & 15) + 1]);
                lane[(c & 15) + 2] = __fmaf_rn(qv.z, kv.z, lane[(c & 15) + 2]);
                lane[(c & 15) + 3] = __fmaf_rn(qv.w, kv.w, lane[(c & 15) + 3]);
            }
            float e = reduce_np16(lane);
            e = e / 8.0f;                      // scale = sqrt(64), exact
            A[r][j] = 1.0f / (1.0f + expf(-e));  // select in sigmoid domain
        }
    }

    const long long obase = (long long)(b * NN + row_base + wrow) * NN;

#pragma unroll
    for (int r = 0; r < 4; ++r) {
        float L[8];
#pragma unroll
        for (int j = 0; j < 8; ++j) L[j] = A[r][j];

        // Batcher odd-even merge sort, 8 elems, descending
        cxf(L[0],L[1]); cxf(L[2],L[3]); cxf(L[4],L[5]); cxf(L[6],L[7]);
        cxf(L[0],L[2]); cxf(L[1],L[3]); cxf(L[4],L[6]); cxf(L[5],L[7]);
        cxf(L[1],L[2]); cxf(L[5],L[6]);
        cxf(L[0],L[4]); cxf(L[1],L[5]); cxf(L[2],L[6]); cxf(L[3],L[7]);
        cxf(L[2],L[4]); cxf(L[3],L[5]);
        cxf(L[1],L[2]); cxf(L[3],L[4]); cxf(L[5],L[6]);

        // 64-lane butterfly merge: global top-8 of the row in every lane
#pragma unroll
        for (int mask = 1; mask < 64; mask <<= 1) {
            float Pr[8], M[8];
#pragma unroll
            for (int j = 0; j < 8; ++j) Pr[j] = __shfl_xor(L[j], mask, 64);
#pragma unroll
            for (int j = 0; j < 8; ++j) M[j] = fmaxf(L[j], Pr[7 - j]);
            cxf(M[0],M[4]); cxf(M[1],M[5]); cxf(M[2],M[6]); cxf(M[3],M[7]);
            cxf(M[0],M[2]); cxf(M[1],M[3]); cxf(M[4],M[6]); cxf(M[5],M[7]);
            cxf(M[0],M[1]); cxf(M[2],M[3]); cxf(M[4],M[5]); cxf(M[6],M[7]);
#pragma unroll
            for (int j = 0; j < 8; ++j) L[j] = M[j];
        }
        const float kth = L[7];

        float* orow = outp + obase + (long long)r * NN;
#pragma unroll
        for (int j = 0; j < 8; ++j)
            orow[(j << 6) + l] = (A[r][j] >= kth) ? A[r][j] : 0.0f;
    }
}

extern "C" void kernel_launch(void* const* d_in, const int* in_sizes, int n_in,
                              void* d_out, int out_size, void* d_ws, size_t ws_size,
                              hipStream_t stream) {
    const float* x     = (const float*)d_in[0];
    const float* Ws    = (const float*)d_in[1];
    const float* Wphi  = (const float*)d_in[2];
    const float* b_phi = (const float*)d_in[3];
    const float* Wmu   = (const float*)d_in[4];
    const float* b_mu  = (const float*)d_in[5];
    const float* WQ    = (const float*)d_in[6];
    const float* WK    = (const float*)d_in[7];
    float* out = (float*)d_out;

    // Q/K handoff in d_ws (8 MB); fully rewritten by k1 each call -> deterministic.
    float* gQ = (float*)d_ws;
    float* gK = gQ + (long long)BB * NN * DD;

    hipLaunchKernelGGL(k1, dim3(8192), dim3(512), 0, stream,
                       x, Ws, Wphi, b_phi, Wmu, b_mu, WQ, WK, gQ, gK);
    hipLaunchKernelGGL(k2f, dim3(1024), dim3(256), 0, stream, gQ, gK, out);
}

// Round 17
// 385.933 us; speedup vs baseline: 1.1800x; 1.1800x over previous
//
#include <hip/hip_runtime.h>
#include <math.h>

#define BB 16
#define NN 512
#define TT 32
#define CC 128
#define RR 32
#define DD 64

// numpy npyv(AVX512) einsum contig-two dot emulation (FROZEN CONTRACT):
// 16-lane FMA accumulator over ascending 16-blocks + _mm512_reduce_add_ps tree.
__device__ __forceinline__ float dot_np16(const float* __restrict__ a,
                                          const float* __restrict__ b, int n) {
    float lane[16];
#pragma unroll
    for (int l = 0; l < 16; ++l) lane[l] = 0.0f;
    for (int i = 0; i < n; i += 16) {
#pragma unroll
        for (int l = 0; l < 16; ++l)
            lane[l] = __fmaf_rn(a[i + l], b[i + l], lane[l]);
    }
    float m[8], p[4];
#pragma unroll
    for (int i = 0; i < 8; ++i) m[i] = __fadd_rn(lane[i], lane[i + 8]);
#pragma unroll
    for (int i = 0; i < 4; ++i) p[i] = __fadd_rn(m[i], m[i + 4]);
    float q0 = __fadd_rn(p[0], p[2]);
    float q1 = __fadd_rn(p[1], p[3]);
    return __fadd_rn(q0, q1);
}

__device__ __forceinline__ float reduce_np16(const float (&lane)[16]) {
    float m[8], p[4];
#pragma unroll
    for (int i = 0; i < 8; ++i) m[i] = __fadd_rn(lane[i], lane[i + 8]);
#pragma unroll
    for (int i = 0; i < 4; ++i) p[i] = __fadd_rn(m[i], m[i + 4]);
    float q0 = __fadd_rn(p[0], p[2]);
    float q1 = __fadd_rn(p[1], p[3]);
    return __fadd_rn(q0, q1);
}

#define XS2 132   // mult of 4: 16B-aligned rows; b128 row-varying reads bank-balanced (r11/r12: 0 conflicts)

// ------------- Kernel 1: per-(b,n) pipeline -> Q,K (fp32-faithful) -----------
// 512 threads. z_ta slot-split (r13-verified combine) with LDS operands:
// thread (t = tid&31, h = bit5, q = tid>>6) accumulates slots 8h..8h+7 of rows
// {q+8j}: acc = 32 VGPR, xv b128 reused over 4 rows, Wss reads are 2-address
// broadcasts. 80 b128/wave, 640/block vs r12's 1024 (the measured k1 cost).
__global__ __launch_bounds__(512) void k1(const float* __restrict__ x,
        const float* __restrict__ Ws, const float* __restrict__ Wphi,
        const float* __restrict__ b_phi, const float* __restrict__ Wmu,
        const float* __restrict__ b_mu, const float* __restrict__ WQ,
        const float* __restrict__ WK,
        float* __restrict__ gQ, float* __restrict__ gK)
{
    __shared__ float Xs[TT * XS2];    // 16.9 KB (X, later X_hat in place)
    __shared__ float Wss[RR * XS2];   // 16.9 KB (staged Ws)
    __shared__ float zta[TT * 33];    // 4.2 KB
    __shared__ float xc[CC];          // avg, later X_c
    __shared__ float wsh[CC];
    __shared__ float zca[RR];
    __shared__ float lg[TT];
    __shared__ float alpha[TT];

    const int tid = threadIdx.x;      // 0..511
    const int bn = blockIdx.x;
    const float* xb = x + (long long)bn * (TT * CC);

    // float4 staging of X and Ws (coalesced global, aligned LDS)
#pragma unroll
    for (int k = 0; k < 2; ++k) {
        int idx = tid + (k << 9);          // float4 idx 0..1023
        int t  = idx >> 5;
        int c4 = (idx & 31) << 2;
        *(float4*)&Xs[t * XS2 + c4]  = ((const float4*)xb)[idx];
        *(float4*)&Wss[t * XS2 + c4] = ((const float4*)Ws)[idx];
    }
    __syncthreads();

    // avg = np.mean over t (pairwise 8-acc), /32   [r12 exact]
    if (tid < CC) {
        float r[8];
#pragma unroll
        for (int j = 0; j < 8; ++j) r[j] = Xs[j * XS2 + tid];
#pragma unroll
        for (int i = 8; i < 32; i += 8)
#pragma unroll
            for (int j = 0; j < 8; ++j) r[j] = __fadd_rn(r[j], Xs[(i + j) * XS2 + tid]);
        float s = __fadd_rn(__fadd_rn(__fadd_rn(r[0], r[1]), __fadd_rn(r[2], r[3])),
                            __fadd_rn(__fadd_rn(r[4], r[5]), __fadd_rn(r[6], r[7])));
        xc[tid] = s / 32.0f;               // xc holds avg
    }
    __syncthreads();

    // z_ca = relu(avg . Ws[r,:])   [r12 exact, Wss]
    if (tid < RR) {
        const float* wr = &Wss[tid * XS2];
        float lane[16];
#pragma unroll
        for (int l = 0; l < 16; ++l) lane[l] = 0.0f;
#pragma unroll
        for (int c = 0; c < CC; c += 4) {
            float4 av = *(const float4*)&xc[c];
            float4 wv = *(const float4*)&wr[c];
            lane[(c & 15) + 0] = __fmaf_rn(av.x, wv.x, lane[(c & 15) + 0]);
            lane[(c & 15) + 1] = __fmaf_rn(av.y, wv.y, lane[(c & 15) + 1]);
            lane[(c & 15) + 2] = __fmaf_rn(av.z, wv.z, lane[(c & 15) + 2]);
            lane[(c & 15) + 3] = __fmaf_rn(av.w, wv.w, lane[(c & 15) + 3]);
        }
        zca[tid] = fmaxf(reduce_np16(lane), 0.0f);
    }
    __syncthreads();

    // w = sigmoid(zca . Wphi[c,:] + b_phi)   [r12 exact]
    if (tid < CC) {
        float t = __fadd_rn(dot_np16(zca, Wphi + tid * RR, RR), b_phi[tid]);
        wsh[tid] = 1.0f / (1.0f + expf(-t));
    }
    __syncthreads();

    // X_hat in place: Xs <- __fmul_rn(Xs, wsh)  (4096 elems, 8 per thread)
#pragma unroll
    for (int k = 0; k < 8; ++k) {
        int i = tid + (k << 9);
        int t = i >> 7, c = i & 127;
        Xs[t * XS2 + c] = __fmul_rn(Xs[t * XS2 + c], wsh[c]);
    }
    __syncthreads();

    // z_ta = relu(X_hat . Ws^T), slot-split across lane halves (r13-verified):
    // thread (t, h, q) owns slots 8h..8h+7 of rows q+8j, j=0..3.
    {
        const int t = tid & 31;
        const int h = (tid >> 5) & 1;
        const int q = tid >> 6;                // 0..7
        const float* xr = &Xs[t * XS2 + 8 * h];
        float acc[4][8];
#pragma unroll
        for (int j = 0; j < 4; ++j)
#pragma unroll
            for (int u = 0; u < 8; ++u) acc[j][u] = 0.0f;

#pragma unroll
        for (int m = 0; m < 8; ++m) {          // chunks of 16 c's
            float4 xv0 = *(const float4*)&xr[m * 16 + 0];
            float4 xv1 = *(const float4*)&xr[m * 16 + 4];
#pragma unroll
            for (int j = 0; j < 4; ++j) {
                const float* wp = &Wss[(q + 8 * j) * XS2 + 8 * h + m * 16];
                float4 wv0 = *(const float4*)&wp[0];
                float4 wv1 = *(const float4*)&wp[4];
                acc[j][0] = __fmaf_rn(xv0.x, wv0.x, acc[j][0]);
                acc[j][1] = __fmaf_rn(xv0.y, wv0.y, acc[j][1]);
                acc[j][2] = __fmaf_rn(xv0.z, wv0.z, acc[j][2]);
                acc[j][3] = __fmaf_rn(xv0.w, wv0.w, acc[j][3]);
                acc[j][4] = __fmaf_rn(xv1.x, wv1.x, acc[j][4]);
                acc[j][5] = __fmaf_rn(xv1.y, wv1.y, acc[j][5]);
                acc[j][6] = __fmaf_rn(xv1.z, wv1.z, acc[j][6]);
                acc[j][7] = __fmaf_rn(xv1.w, wv1.w, acc[j][7]);
            }
        }
        // combine: first tree level across the h-pair via shfl, rest on h==0
#pragma unroll
        for (int j = 0; j < 4; ++j) {
            float oth[8];
#pragma unroll
            for (int u = 0; u < 8; ++u) oth[u] = __shfl_xor(acc[j][u], 32, 64);
            if (h == 0) {
                float m8[8], p[4];
#pragma unroll
                for (int u = 0; u < 8; ++u) m8[u] = __fadd_rn(acc[j][u], oth[u]);
#pragma unroll
                for (int u = 0; u < 4; ++u) p[u] = __fadd_rn(m8[u], m8[u + 4]);
                float q0 = __fadd_rn(p[0], p[2]);
                float q1 = __fadd_rn(p[1], p[3]);
                zta[t * 33 + q + 8 * j] = fmaxf(__fadd_rn(q0, q1), 0.0f);
            }
        }
    }
    __syncthreads();

    // logits
    if (tid < TT) lg[tid] = __fadd_rn(dot_np16(&zta[tid * 33], Wmu, RR), b_mu[0]);
    __syncthreads();

    // softmax over t (max exact; pairwise 8-acc sum like np)
    if (tid == 0) {
        float m = lg[0];
        for (int t = 1; t < TT; ++t) m = fmaxf(m, lg[t]);
        float e[TT];
        for (int t = 0; t < TT; ++t) e[t] = expf(__fsub_rn(lg[t], m));
        float r[8];
#pragma unroll
        for (int j = 0; j < 8; ++j) r[j] = e[j];
#pragma unroll
        for (int i = 8; i < 32; i += 8)
#pragma unroll
            for (int j = 0; j < 8; ++j) r[j] = __fadd_rn(r[j], e[i + j]);
        float s = __fadd_rn(__fadd_rn(__fadd_rn(r[0], r[1]), __fadd_rn(r[2], r[3])),
                            __fadd_rn(__fadd_rn(r[4], r[5]), __fadd_rn(r[6], r[7])));
        for (int t = 0; t < TT; ++t) alpha[t] = e[t] / s;
    }
    __syncthreads();

    // X_c = einsum('t,tc->c', alpha, X_hat): sequential FMA on in-place X_hat
    if (tid < CC) {
        float s = 0.0f;
        for (int t = 0; t < TT; ++t)
            s = __fmaf_rn(alpha[t], Xs[t * XS2 + tid], s);
        xc[tid] = s;
    }
    __syncthreads();

    // Q, K projections
    if (tid < 128) {
        int isK = tid >> 6, d = tid & 63;
        const float* Wr = (isK ? WK : WQ) + d * CC;
        float s = dot_np16(xc, Wr, CC);
        if (isK) gK[bn * DD + d] = s;
        else     gQ[bn * DD + d] = s;
    }
}

// ------------- Kernel 2: E rows (np-order fp32) + sigmoid-domain top-8 -------
__device__ __forceinline__ void cxf(float& a, float& b) {
    float mx = fmaxf(a, b), mn = fminf(a, b);
    a = mx; b = mn;
}

#define KS 68   // Kch row stride: mult of 4 (aligned b128), uniform banks

__global__ __launch_bounds__(256) void k2f(const float* __restrict__ gQ,
                                           const float* __restrict__ gK,
                                           float* __restrict__ out)
{
    __shared__ float Qs[16][64];
    __shared__ float Kch[64 * KS];

    const int tid = threadIdx.x;
    const int gid = blockIdx.x;
    const int dir = gid & 1;
    const int b   = (gid >> 1) & 15;
    const int grp = gid >> 5;                 // 0..31
    const int row_base = grp << 4;

    const float* Qrow = dir ? gK : gQ;        // backward: rows come from K
    const float* Mat  = dir ? gQ : gK;
    float* outp = out + (long long)dir * BB * NN * NN;

    {   // float4 staging of the 16 query rows
        int row = tid >> 4, c4 = (tid & 15) << 2;
        *(float4*)&Qs[row][c4] =
            ((const float4*)Qrow)[(long long)(b * NN + row_base + row) * 16 + (tid & 15)];
    }

    const int l = tid & 63, w = tid >> 6, wrow = w << 2;
    float A[4][8];

#pragma unroll
    for (int j = 0; j < 8; ++j) {             // 8 column chunks of 64
        __syncthreads();                       // covers Qs on j==0, Kch reuse after
#pragma unroll
        for (int k = 0; k < 4; ++k) {          // float4 staging of 64x64 chunk
            int idx = tid + (k << 8);          // 0..1023
            int row = idx >> 4, c4 = (idx & 15) << 2;
            *(float4*)&Kch[row * KS + c4] =
                ((const float4*)Mat)[(long long)(b * NN + (j << 6) + row) * 16 + (idx & 15)];
        }
        __syncthreads();
#pragma unroll
        for (int r = 0; r < 4; ++r) {
            const float* qa = Qs[wrow + r];
            const float* kb = &Kch[l * KS];
            float lane[16];
#pragma unroll
            for (int ll = 0; ll < 16; ++ll) lane[ll] = 0.0f;
#pragma unroll
            for (int c = 0; c < DD; c += 4) {
                float4 qv = *(const float4*)&qa[c];
                float4 kv = *(const float4*)&kb[c];
                lane[(c & 15) + 0] = __fmaf_rn(qv.x, kv.x, lane[(c & 15) + 0]);
                lane[(c & 15) + 1] = __fmaf_rn(qv.y, kv.y, lane[(c & 15) + 1]);
                lane[(c & 15) + 2] = __fmaf_rn(qv.z, kv.z, lane[(c & 15) + 2]);
                lane[(c & 15) + 3] = __fmaf_rn(qv.w, kv.w, lane[(c & 15) + 3]);
            }
            float e = reduce_np16(lane);
            e = e / 8.0f;                      // scale = sqrt(64), exact
            A[r][j] = 1.0f / (1.0f + expf(-e));  // select in sigmoid domain
        }
    }

    const long long obase = (long long)(b * NN + row_base + wrow) * NN;

#pragma unroll
    for (int r = 0; r < 4; ++r) {
        float L[8];
#pragma unroll
        for (int j = 0; j < 8; ++j) L[j] = A[r][j];

        // Batcher odd-even merge sort, 8 elems, descending
        cxf(L[0],L[1]); cxf(L[2],L[3]); cxf(L[4],L[5]); cxf(L[6],L[7]);
        cxf(L[0],L[2]); cxf(L[1],L[3]); cxf(L[4],L[6]); cxf(L[5],L[7]);
        cxf(L[1],L[2]); cxf(L[5],L[6]);
        cxf(L[0],L[4]); cxf(L[1],L[5]); cxf(L[2],L[6]); cxf(L[3],L[7]);
        cxf(L[2],L[4]); cxf(L[3],L[5]);
        cxf(L[1],L[2]); cxf(L[3],L[4]); cxf(L[5],L[6]);

        // 64-lane butterfly merge: global top-8 of the row in every lane
#pragma unroll
        for (int mask = 1; mask < 64; mask <<= 1) {
            float Pr[8], M[8];
#pragma unroll
            for (int j = 0; j < 8; ++j) Pr[j] = __shfl_xor(L[j], mask, 64);
#pragma unroll
            for (int j = 0; j < 8; ++j) M[j] = fmaxf(L[j], Pr[7 - j]);
            cxf(M[0],M[4]); cxf(M[1],M[5]); cxf(M[2],M[6]); cxf(M[3],M[7]);
            cxf(M[0],M[2]); cxf(M[1],M[3]); cxf(M[4],M[6]); cxf(M[5],M[7]);
            cxf(M[0],M[1]); cxf(M[2],M[3]); cxf(M[4],M[5]); cxf(M[6],M[7]);
#pragma unroll
            for (int j = 0; j < 8; ++j) L[j] = M[j];
        }
        const float kth = L[7];

        float* orow = outp + obase + (long long)r * NN;
#pragma unroll
        for (int j = 0; j < 8; ++j)
            orow[(j << 6) + l] = (A[r][j] >= kth) ? A[r][j] : 0.0f;
    }
}

extern "C" void kernel_launch(void* const* d_in, const int* in_sizes, int n_in,
                              void* d_out, int out_size, void* d_ws, size_t ws_size,
                              hipStream_t stream) {
    const float* x     = (const float*)d_in[0];
    const float* Ws    = (const float*)d_in[1];
    const float* Wphi  = (const float*)d_in[2];
    const float* b_phi = (const float*)d_in[3];
    const float* Wmu   = (const float*)d_in[4];
    const float* b_mu  = (const float*)d_in[5];
    const float* WQ    = (const float*)d_in[6];
    const float* WK    = (const float*)d_in[7];
    float* out = (float*)d_out;

    // Q/K handoff in d_ws (8 MB); fully rewritten by k1 each call -> deterministic.
    float* gQ = (float*)d_ws;
    float* gK = gQ + (long long)BB * NN * DD;

    hipLaunchKernelGGL(k1, dim3(8192), dim3(512), 0, stream,
                       x, Ws, Wphi, b_phi, Wmu, b_mu, WQ, WK, gQ, gK);
    hipLaunchKernelGGL(k2f, dim3(1024), dim3(256), 0, stream, gQ, gK, out);
}

// Round 18
// 290.831 us; speedup vs baseline: 1.5658x; 1.3270x over previous
//
#include <hip/hip_runtime.h>
#include <math.h>

#define BB 16
#define NN 512
#define TT 32
#define CC 128
#define RR 32
#define DD 64

// numpy npyv(AVX512) einsum contig-two dot emulation (FROZEN CONTRACT):
// 16-lane FMA accumulator over ascending 16-blocks + _mm512_reduce_add_ps tree.
__device__ __forceinline__ float dot_np16(const float* __restrict__ a,
                                          const float* __restrict__ b, int n) {
    float lane[16];
#pragma unroll
    for (int l = 0; l < 16; ++l) lane[l] = 0.0f;
    for (int i = 0; i < n; i += 16) {
#pragma unroll
        for (int l = 0; l < 16; ++l)
            lane[l] = __fmaf_rn(a[i + l], b[i + l], lane[l]);
    }
    float m[8], p[4];
#pragma unroll
    for (int i = 0; i < 8; ++i) m[i] = __fadd_rn(lane[i], lane[i + 8]);
#pragma unroll
    for (int i = 0; i < 4; ++i) p[i] = __fadd_rn(m[i], m[i + 4]);
    float q0 = __fadd_rn(p[0], p[2]);
    float q1 = __fadd_rn(p[1], p[3]);
    return __fadd_rn(q0, q1);
}

__device__ __forceinline__ float reduce_np16(const float (&lane)[16]) {
    float m[8], p[4];
#pragma unroll
    for (int i = 0; i < 8; ++i) m[i] = __fadd_rn(lane[i], lane[i + 8]);
#pragma unroll
    for (int i = 0; i < 4; ++i) p[i] = __fadd_rn(m[i], m[i + 4]);
    float q0 = __fadd_rn(p[0], p[2]);
    float q1 = __fadd_rn(p[1], p[3]);
    return __fadd_rn(q0, q1);
}

#define XS2 132   // mult of 4: 16B-aligned rows; b128 row-varying reads bank-balanced (r11/r12: 0 conflicts)

// ------------- Kernel 1: per-(b,n) pipeline -> Q,K (fp32-faithful) -----------
// EXACT r12 code shape (the one compilation the allocator handles cleanly at
// VGPR 64), with ONE change: Ws is never staged in LDS. z_ca/z_ta read it from
// global (2 distinct 64B lines per wave-load -> L1 broadcast, VMEM pipe; Ws is
// 16KB, L1/L2-resident). LDS 38.5 -> ~23 KB => 7 blocks/CU (was 4): the
// latency-bound symptom (occ 37%, VALU 33%, HBM 5%) gets more waves.
__global__ __launch_bounds__(256) void k1(const float* __restrict__ x,
        const float* __restrict__ Ws, const float* __restrict__ Wphi,
        const float* __restrict__ b_phi, const float* __restrict__ Wmu,
        const float* __restrict__ b_mu, const float* __restrict__ WQ,
        const float* __restrict__ WK,
        float* __restrict__ gQ, float* __restrict__ gK)
{
    __shared__ float Xs[TT * XS2];    // 16.9 KB  (X, later X_hat in place)
    __shared__ float zta[TT * 33];    // 4.2 KB
    __shared__ float xc[CC];          // avg, later X_c
    __shared__ float wsh[CC];
    __shared__ float zca[RR];
    __shared__ float lg[TT];
    __shared__ float alpha[TT];

    const int tid = threadIdx.x;
    const int bn = blockIdx.x;
    const float* xb = x + (long long)bn * (TT * CC);

    // float4 staging of X (coalesced global, aligned LDS)
#pragma unroll
    for (int k = 0; k < 4; ++k) {
        int idx = tid + (k << 8);          // float4 idx 0..1023
        int t  = idx >> 5;
        int c4 = (idx & 31) << 2;
        *(float4*)&Xs[t * XS2 + c4] = ((const float4*)xb)[idx];
    }
    __syncthreads();

    // avg = np.mean over t (pairwise 8-acc), /32   [r12 exact]
    if (tid < CC) {
        float r[8];
#pragma unroll
        for (int j = 0; j < 8; ++j) r[j] = Xs[j * XS2 + tid];
#pragma unroll
        for (int i = 8; i < 32; i += 8)
#pragma unroll
            for (int j = 0; j < 8; ++j) r[j] = __fadd_rn(r[j], Xs[(i + j) * XS2 + tid]);
        float s = __fadd_rn(__fadd_rn(__fadd_rn(r[0], r[1]), __fadd_rn(r[2], r[3])),
                            __fadd_rn(__fadd_rn(r[4], r[5]), __fadd_rn(r[6], r[7])));
        xc[tid] = s / 32.0f;               // xc holds avg
    }
    __syncthreads();

    // z_ca = relu(avg . Ws[r,:]) -- Ws from GLOBAL (r15-verified bitwise)
    if (tid < RR) {
        const float* wr = Ws + tid * CC;
        float lane[16];
#pragma unroll
        for (int l = 0; l < 16; ++l) lane[l] = 0.0f;
#pragma unroll
        for (int c = 0; c < CC; c += 4) {
            float4 av = *(const float4*)&xc[c];
            float4 wv = *(const float4*)&wr[c];
            lane[(c & 15) + 0] = __fmaf_rn(av.x, wv.x, lane[(c & 15) + 0]);
            lane[(c & 15) + 1] = __fmaf_rn(av.y, wv.y, lane[(c & 15) + 1]);
            lane[(c & 15) + 2] = __fmaf_rn(av.z, wv.z, lane[(c & 15) + 2]);
            lane[(c & 15) + 3] = __fmaf_rn(av.w, wv.w, lane[(c & 15) + 3]);
        }
        zca[tid] = fmaxf(reduce_np16(lane), 0.0f);
    }
    __syncthreads();

    // w = sigmoid(zca . Wphi[c,:] + b_phi)   [r12 exact]
    if (tid < CC) {
        float t = __fadd_rn(dot_np16(zca, Wphi + tid * RR, RR), b_phi[tid]);
        wsh[tid] = 1.0f / (1.0f + expf(-t));
    }
    __syncthreads();

    // X_hat in place: Xs <- __fmul_rn(Xs, wsh)   [r12 exact]
#pragma unroll
    for (int k = 0; k < 16; ++k) {
        int i = tid + (k << 8);
        int t = i >> 7, c = i & 127;
        Xs[t * XS2 + c] = __fmul_rn(Xs[t * XS2 + c], wsh[c]);
    }
    __syncthreads();

    // z_ta = relu(X_hat . Ws^T): r12's exact loop shape (thread t=tid&31,
    // q=tid>>5; rows q+8j; lane[4][16] -- compiler serializes at VGPR 64).
    // Only change: wv comes from global Ws (wave-broadcast address).
    {
        const int t = tid & 31, q = tid >> 5;
        const float* xr = &Xs[t * XS2];
        float lane[4][16];
#pragma unroll
        for (int j = 0; j < 4; ++j)
#pragma unroll
            for (int l = 0; l < 16; ++l) lane[j][l] = 0.0f;
#pragma unroll
        for (int c = 0; c < CC; c += 4) {
            float4 xv = *(const float4*)&xr[c];
#pragma unroll
            for (int j = 0; j < 4; ++j) {
                float4 wv = *(const float4*)&Ws[(q + 8 * j) * CC + c];
                lane[j][(c & 15) + 0] = __fmaf_rn(xv.x, wv.x, lane[j][(c & 15) + 0]);
                lane[j][(c & 15) + 1] = __fmaf_rn(xv.y, wv.y, lane[j][(c & 15) + 1]);
                lane[j][(c & 15) + 2] = __fmaf_rn(xv.z, wv.z, lane[j][(c & 15) + 2]);
                lane[j][(c & 15) + 3] = __fmaf_rn(xv.w, wv.w, lane[j][(c & 15) + 3]);
            }
        }
#pragma unroll
        for (int j = 0; j < 4; ++j)
            zta[t * 33 + q + 8 * j] = fmaxf(reduce_np16(lane[j]), 0.0f);
    }
    __syncthreads();

    // logits   [r12 exact]
    if (tid < TT) lg[tid] = __fadd_rn(dot_np16(&zta[tid * 33], Wmu, RR), b_mu[0]);
    __syncthreads();

    // softmax over t (max exact; pairwise 8-acc sum like np)   [r12 exact]
    if (tid == 0) {
        float m = lg[0];
        for (int t = 1; t < TT; ++t) m = fmaxf(m, lg[t]);
        float e[TT];
        for (int t = 0; t < TT; ++t) e[t] = expf(__fsub_rn(lg[t], m));
        float r[8];
#pragma unroll
        for (int j = 0; j < 8; ++j) r[j] = e[j];
#pragma unroll
        for (int i = 8; i < 32; i += 8)
#pragma unroll
            for (int j = 0; j < 8; ++j) r[j] = __fadd_rn(r[j], e[i + j]);
        float s = __fadd_rn(__fadd_rn(__fadd_rn(r[0], r[1]), __fadd_rn(r[2], r[3])),
                            __fadd_rn(__fadd_rn(r[4], r[5]), __fadd_rn(r[6], r[7])));
        for (int t = 0; t < TT; ++t) alpha[t] = e[t] / s;
    }
    __syncthreads();

    // X_c = einsum('t,tc->c', alpha, X_hat)   [r12 exact]
    if (tid < CC) {
        float s = 0.0f;
        for (int t = 0; t < TT; ++t)
            s = __fmaf_rn(alpha[t], Xs[t * XS2 + tid], s);
        xc[tid] = s;
    }
    __syncthreads();

    // Q, K projections   [r12 exact]
    if (tid < 128) {
        int isK = tid >> 6, d = tid & 63;
        const float* Wr = (isK ? WK : WQ) + d * CC;
        float s = dot_np16(xc, Wr, CC);
        if (isK) gK[bn * DD + d] = s;
        else     gQ[bn * DD + d] = s;
    }
}

// ------------- Kernel 2: E rows (np-order fp32) + sigmoid-domain top-8 -------
__device__ __forceinline__ void cxf(float& a, float& b) {
    float mx = fmaxf(a, b), mn = fminf(a, b);
    a = mx; b = mn;
}

#define KS 68   // Kch row stride: mult of 4 (aligned b128), uniform banks

__global__ __launch_bounds__(256) void k2f(const float* __restrict__ gQ,
                                           const float* __restrict__ gK,
                                           float* __restrict__ out)
{
    __shared__ float Qs[16][64];
    __shared__ float Kch[64 * KS];

    const int tid = threadIdx.x;
    const int gid = blockIdx.x;
    const int dir = gid & 1;
    const int b   = (gid >> 1) & 15;
    const int grp = gid >> 5;                 // 0..31
    const int row_base = grp << 4;

    const float* Qrow = dir ? gK : gQ;        // backward: rows come from K
    const float* Mat  = dir ? gQ : gK;
    float* outp = out + (long long)dir * BB * NN * NN;

    {   // float4 staging of the 16 query rows
        int row = tid >> 4, c4 = (tid & 15) << 2;
        *(float4*)&Qs[row][c4] =
            ((const float4*)Qrow)[(long long)(b * NN + row_base + row) * 16 + (tid & 15)];
    }

    const int l = tid & 63, w = tid >> 6, wrow = w << 2;
    float A[4][8];

#pragma unroll
    for (int j = 0; j < 8; ++j) {             // 8 column chunks of 64
        __syncthreads();                       // covers Qs on j==0, Kch reuse after
#pragma unroll
        for (int k = 0; k < 4; ++k) {          // float4 staging of 64x64 chunk
            int idx = tid + (k << 8);          // 0..1023
            int row = idx >> 4, c4 = (idx & 15) << 2;
            *(float4*)&Kch[row * KS + c4] =
                ((const float4*)Mat)[(long long)(b * NN + (j << 6) + row) * 16 + (idx & 15)];
        }
        __syncthreads();
#pragma unroll
        for (int r = 0; r < 4; ++r) {
            const float* qa = Qs[wrow + r];
            const float* kb = &Kch[l * KS];
            float lane[16];
#pragma unroll
            for (int ll = 0; ll < 16; ++ll) lane[ll] = 0.0f;
#pragma unroll
            for (int c = 0; c < DD; c += 4) {
                float4 qv = *(const float4*)&qa[c];
                float4 kv = *(const float4*)&kb[c];
                lane[(c & 15) + 0] = __fmaf_rn(qv.x, kv.x, lane[(c & 15) + 0]);
                lane[(c & 15) + 1] = __fmaf_rn(qv.y, kv.y, lane[(c & 15) + 1]);
                lane[(c & 15) + 2] = __fmaf_rn(qv.z, kv.z, lane[(c & 15) + 2]);
                lane[(c & 15) + 3] = __fmaf_rn(qv.w, kv.w, lane[(c & 15) + 3]);
            }
            float e = reduce_np16(lane);
            e = e / 8.0f;                      // scale = sqrt(64), exact
            A[r][j] = 1.0f / (1.0f + expf(-e));  // select in sigmoid domain
        }
    }

    const long long obase = (long long)(b * NN + row_base + wrow) * NN;

#pragma unroll
    for (int r = 0; r < 4; ++r) {
        float L[8];
#pragma unroll
        for (int j = 0; j < 8; ++j) L[j] = A[r][j];

        // Batcher odd-even merge sort, 8 elems, descending
        cxf(L[0],L[1]); cxf(L[2],L[3]); cxf(L[4],L[5]); cxf(L[6],L[7]);
        cxf(L[0],L[2]); cxf(L[1],L[3]); cxf(L[4],L[6]); cxf(L[5],L[7]);
        cxf(L[1],L[2]); cxf(L[5],L[6]);
        cxf(L[0],L[4]); cxf(L[1],L[5]); cxf(L[2],L[6]); cxf(L[3],L[7]);
        cxf(L[2],L[4]); cxf(L[3],L[5]);
        cxf(L[1],L[2]); cxf(L[3],L[4]); cxf(L[5],L[6]);

        // 64-lane butterfly merge: global top-8 of the row in every lane
#pragma unroll
        for (int mask = 1; mask < 64; mask <<= 1) {
            float Pr[8], M[8];
#pragma unroll
            for (int j = 0; j < 8; ++j) Pr[j] = __shfl_xor(L[j], mask, 64);
#pragma unroll
            for (int j = 0; j < 8; ++j) M[j] = fmaxf(L[j], Pr[7 - j]);
            cxf(M[0],M[4]); cxf(M[1],M[5]); cxf(M[2],M[6]); cxf(M[3],M[7]);
            cxf(M[0],M[2]); cxf(M[1],M[3]); cxf(M[4],M[6]); cxf(M[5],M[7]);
            cxf(M[0],M[1]); cxf(M[2],M[3]); cxf(M[4],M[5]); cxf(M[6],M[7]);
#pragma unroll
            for (int j = 0; j < 8; ++j) L[j] = M[j];
        }
        const float kth = L[7];

        float* orow = outp + obase + (long long)r * NN;
#pragma unroll
        for (int j = 0; j < 8; ++j)
            orow[(j << 6) + l] = (A[r][j] >= kth) ? A[r][j] : 0.0f;
    }
}

extern "C" void kernel_launch(void* const* d_in, const int* in_sizes, int n_in,
                              void* d_out, int out_size, void* d_ws, size_t ws_size,
                              hipStream_t stream) {
    const float* x     = (const float*)d_in[0];
    const float* Ws    = (const float*)d_in[1];
    const float* Wphi  = (const float*)d_in[2];
    const float* b_phi = (const float*)d_in[3];
    const float* Wmu   = (const float*)d_in[4];
    const float* b_mu  = (const float*)d_in[5];
    const float* WQ    = (const float*)d_in[6];
    const float* WK    = (const float*)d_in[7];
    float* out = (float*)d_out;

    // Q/K handoff in d_ws (8 MB); fully rewritten by k1 each call -> deterministic.
    float* gQ = (float*)d_ws;
    float* gK = gQ + (long long)BB * NN * DD;

    hipLaunchKernelGGL(k1, dim3(8192), dim3(256), 0, stream,
                       x, Ws, Wphi, b_phi, Wmu, b_mu, WQ, WK, gQ, gK);
    hipLaunchKernelGGL(k2f, dim3(1024), dim3(256), 0, stream, gQ, gK, out);
}

// Round 19
// 233.258 us; speedup vs baseline: 1.9523x; 1.2468x over previous
//
#include <hip/hip_runtime.h>
#include <math.h>

#define BB 16
#define NN 512
#define TT 32
#define CC 128
#define RR 32
#define DD 64

// numpy npyv(AVX512) einsum contig-two dot emulation (FROZEN CONTRACT):
// 16-lane FMA accumulator over ascending 16-blocks + _mm512_reduce_add_ps tree.
__device__ __forceinline__ float dot_np16(const float* __restrict__ a,
                                          const float* __restrict__ b, int n) {
    float lane[16];
#pragma unroll
    for (int l = 0; l < 16; ++l) lane[l] = 0.0f;
    for (int i = 0; i < n; i += 16) {
#pragma unroll
        for (int l = 0; l < 16; ++l)
            lane[l] = __fmaf_rn(a[i + l], b[i + l], lane[l]);
    }
    float m[8], p[4];
#pragma unroll
    for (int i = 0; i < 8; ++i) m[i] = __fadd_rn(lane[i], lane[i + 8]);
#pragma unroll
    for (int i = 0; i < 4; ++i) p[i] = __fadd_rn(m[i], m[i + 4]);
    float q0 = __fadd_rn(p[0], p[2]);
    float q1 = __fadd_rn(p[1], p[3]);
    return __fadd_rn(q0, q1);
}

__device__ __forceinline__ float reduce_np16(const float (&lane)[16]) {
    float m[8], p[4];
#pragma unroll
    for (int i = 0; i < 8; ++i) m[i] = __fadd_rn(lane[i], lane[i + 8]);
#pragma unroll
    for (int i = 0; i < 4; ++i) p[i] = __fadd_rn(m[i], m[i + 4]);
    float q0 = __fadd_rn(p[0], p[2]);
    float q1 = __fadd_rn(p[1], p[3]);
    return __fadd_rn(q0, q1);
}

#define XS2 132   // mult of 4: 16B-aligned rows; b128 row-varying reads bank-balanced (r11/r12: 0 conflicts)

// ------------- Kernel 1: per-(b,n) pipeline -> Q,K (fp32-faithful) -----------
// r12's configuration (both z_ta operands in LDS -- the only one the allocator
// compiles cleanly) with z_ta split into TWO explicit lane[2][16] row-groups:
// 32 acc VGPRs live (fits the 64 budget) and xv is read once per 2 rows
// instead of once per row: 192 LDS insts/thread vs r12's serialized 256.
__global__ __launch_bounds__(256) void k1(const float* __restrict__ x,
        const float* __restrict__ Ws, const float* __restrict__ Wphi,
        const float* __restrict__ b_phi, const float* __restrict__ Wmu,
        const float* __restrict__ b_mu, const float* __restrict__ WQ,
        const float* __restrict__ WK,
        float* __restrict__ gQ, float* __restrict__ gK)
{
    __shared__ float Xs[TT * XS2];    // 16.9 KB (X, later X_hat in place)
    __shared__ float Wss[RR * XS2];   // 16.9 KB (staged Ws)
    __shared__ float zta[TT * 33];    // 4.2 KB
    __shared__ float xc[CC];          // avg, later X_c
    __shared__ float wsh[CC];
    __shared__ float zca[RR];
    __shared__ float lg[TT];
    __shared__ float alpha[TT];

    const int tid = threadIdx.x;
    const int bn = blockIdx.x;
    const float* xb = x + (long long)bn * (TT * CC);

    // float4 staging of X and Ws (coalesced global, aligned LDS)  [r12 exact]
#pragma unroll
    for (int k = 0; k < 4; ++k) {
        int idx = tid + (k << 8);          // float4 idx 0..1023
        int t  = idx >> 5;
        int c4 = (idx & 31) << 2;
        *(float4*)&Xs[t * XS2 + c4]  = ((const float4*)xb)[idx];
        *(float4*)&Wss[t * XS2 + c4] = ((const float4*)Ws)[idx];
    }
    __syncthreads();

    // avg = np.mean over t (pairwise 8-acc), /32   [r12 exact]
    if (tid < CC) {
        float r[8];
#pragma unroll
        for (int j = 0; j < 8; ++j) r[j] = Xs[j * XS2 + tid];
#pragma unroll
        for (int i = 8; i < 32; i += 8)
#pragma unroll
            for (int j = 0; j < 8; ++j) r[j] = __fadd_rn(r[j], Xs[(i + j) * XS2 + tid]);
        float s = __fadd_rn(__fadd_rn(__fadd_rn(r[0], r[1]), __fadd_rn(r[2], r[3])),
                            __fadd_rn(__fadd_rn(r[4], r[5]), __fadd_rn(r[6], r[7])));
        xc[tid] = s / 32.0f;               // xc holds avg
    }
    __syncthreads();

    // z_ca = relu(avg . Ws[r,:])   [r12 exact, Wss]
    if (tid < RR) {
        const float* wr = &Wss[tid * XS2];
        float lane[16];
#pragma unroll
        for (int l = 0; l < 16; ++l) lane[l] = 0.0f;
#pragma unroll
        for (int c = 0; c < CC; c += 4) {
            float4 av = *(const float4*)&xc[c];
            float4 wv = *(const float4*)&wr[c];
            lane[(c & 15) + 0] = __fmaf_rn(av.x, wv.x, lane[(c & 15) + 0]);
            lane[(c & 15) + 1] = __fmaf_rn(av.y, wv.y, lane[(c & 15) + 1]);
            lane[(c & 15) + 2] = __fmaf_rn(av.z, wv.z, lane[(c & 15) + 2]);
            lane[(c & 15) + 3] = __fmaf_rn(av.w, wv.w, lane[(c & 15) + 3]);
        }
        zca[tid] = fmaxf(reduce_np16(lane), 0.0f);
    }
    __syncthreads();

    // w = sigmoid(zca . Wphi[c,:] + b_phi)   [r12 exact]
    if (tid < CC) {
        float t = __fadd_rn(dot_np16(zca, Wphi + tid * RR, RR), b_phi[tid]);
        wsh[tid] = 1.0f / (1.0f + expf(-t));
    }
    __syncthreads();

    // X_hat in place: Xs <- __fmul_rn(Xs, wsh)   [r12 exact]
#pragma unroll
    for (int k = 0; k < 16; ++k) {
        int i = tid + (k << 8);
        int t = i >> 7, c = i & 127;
        Xs[t * XS2 + c] = __fmul_rn(Xs[t * XS2 + c], wsh[c]);
    }
    __syncthreads();

    // z_ta = relu(X_hat . Ws^T): thread (t = tid&31, q = tid>>5), rows q+8j.
    // TWO explicit 2-row groups: acc 32 VGPR, xv b128 read once per group.
    {
        const int t = tid & 31, q = tid >> 5;
        const float* xr = &Xs[t * XS2];
#pragma unroll
        for (int g = 0; g < 2; ++g) {
            const float* w0 = &Wss[(q + 8 * (2 * g + 0)) * XS2];
            const float* w1 = &Wss[(q + 8 * (2 * g + 1)) * XS2];
            float l0[16], l1[16];
#pragma unroll
            for (int l = 0; l < 16; ++l) { l0[l] = 0.0f; l1[l] = 0.0f; }
#pragma unroll
            for (int c = 0; c < CC; c += 4) {
                float4 xv = *(const float4*)&xr[c];
                float4 a4 = *(const float4*)&w0[c];
                float4 b4 = *(const float4*)&w1[c];
                int s = c & 15;
                l0[s + 0] = __fmaf_rn(xv.x, a4.x, l0[s + 0]);
                l0[s + 1] = __fmaf_rn(xv.y, a4.y, l0[s + 1]);
                l0[s + 2] = __fmaf_rn(xv.z, a4.z, l0[s + 2]);
                l0[s + 3] = __fmaf_rn(xv.w, a4.w, l0[s + 3]);
                l1[s + 0] = __fmaf_rn(xv.x, b4.x, l1[s + 0]);
                l1[s + 1] = __fmaf_rn(xv.y, b4.y, l1[s + 1]);
                l1[s + 2] = __fmaf_rn(xv.z, b4.z, l1[s + 2]);
                l1[s + 3] = __fmaf_rn(xv.w, b4.w, l1[s + 3]);
            }
            zta[t * 33 + q + 8 * (2 * g + 0)] = fmaxf(reduce_np16(l0), 0.0f);
            zta[t * 33 + q + 8 * (2 * g + 1)] = fmaxf(reduce_np16(l1), 0.0f);
        }
    }
    __syncthreads();

    // logits   [r12 exact]
    if (tid < TT) lg[tid] = __fadd_rn(dot_np16(&zta[tid * 33], Wmu, RR), b_mu[0]);
    __syncthreads();

    // softmax over t (max exact; pairwise 8-acc sum like np)   [r12 exact]
    if (tid == 0) {
        float m = lg[0];
        for (int t = 1; t < TT; ++t) m = fmaxf(m, lg[t]);
        float e[TT];
        for (int t = 0; t < TT; ++t) e[t] = expf(__fsub_rn(lg[t], m));
        float r[8];
#pragma unroll
        for (int j = 0; j < 8; ++j) r[j] = e[j];
#pragma unroll
        for (int i = 8; i < 32; i += 8)
#pragma unroll
            for (int j = 0; j < 8; ++j) r[j] = __fadd_rn(r[j], e[i + j]);
        float s = __fadd_rn(__fadd_rn(__fadd_rn(r[0], r[1]), __fadd_rn(r[2], r[3])),
                            __fadd_rn(__fadd_rn(r[4], r[5]), __fadd_rn(r[6], r[7])));
        for (int t = 0; t < TT; ++t) alpha[t] = e[t] / s;
    }
    __syncthreads();

    // X_c = einsum('t,tc->c', alpha, X_hat)   [r12 exact]
    if (tid < CC) {
        float s = 0.0f;
        for (int t = 0; t < TT; ++t)
            s = __fmaf_rn(alpha[t], Xs[t * XS2 + tid], s);
        xc[tid] = s;
    }
    __syncthreads();

    // Q, K projections   [r12 exact]
    if (tid < 128) {
        int isK = tid >> 6, d = tid & 63;
        const float* Wr = (isK ? WK : WQ) + d * CC;
        float s = dot_np16(xc, Wr, CC);
        if (isK) gK[bn * DD + d] = s;
        else     gQ[bn * DD + d] = s;
    }
}

// ------------- Kernel 2: E rows (np-order fp32) + sigmoid-domain top-8 -------
__device__ __forceinline__ void cxf(float& a, float& b) {
    float mx = fmaxf(a, b), mn = fminf(a, b);
    a = mx; b = mn;
}

#define KS 68   // Kch row stride: mult of 4 (aligned b128), uniform banks

__global__ __launch_bounds__(256) void k2f(const float* __restrict__ gQ,
                                           const float* __restrict__ gK,
                                           float* __restrict__ out)
{
    __shared__ float Qs[16][64];
    __shared__ float Kch[64 * KS];

    const int tid = threadIdx.x;
    const int gid = blockIdx.x;
    const int dir = gid & 1;
    const int b   = (gid >> 1) & 15;
    const int grp = gid >> 5;                 // 0..31
    const int row_base = grp << 4;

    const float* Qrow = dir ? gK : gQ;        // backward: rows come from K
    const float* Mat  = dir ? gQ : gK;
    float* outp = out + (long long)dir * BB * NN * NN;

    {   // float4 staging of the 16 query rows
        int row = tid >> 4, c4 = (tid & 15) << 2;
        *(float4*)&Qs[row][c4] =
            ((const float4*)Qrow)[(long long)(b * NN + row_base + row) * 16 + (tid & 15)];
    }

    const int l = tid & 63, w = tid >> 6, wrow = w << 2;
    float A[4][8];

#pragma unroll
    for (int j = 0; j < 8; ++j) {             // 8 column chunks of 64
        __syncthreads();                       // covers Qs on j==0, Kch reuse after
#pragma unroll
        for (int k = 0; k < 4; ++k) {          // float4 staging of 64x64 chunk
            int idx = tid + (k << 8);          // 0..1023
            int row = idx >> 4, c4 = (idx & 15) << 2;
            *(float4*)&Kch[row * KS + c4] =
                ((const float4*)Mat)[(long long)(b * NN + (j << 6) + row) * 16 + (idx & 15)];
        }
        __syncthreads();
        // two 2-row groups: kb (lane's K-row) read ONCE per group, shared by 2 dots
#pragma unroll
        for (int rg = 0; rg < 2; ++rg) {
            const float* qa0 = Qs[wrow + 2 * rg + 0];
            const float* qa1 = Qs[wrow + 2 * rg + 1];
            const float* kb  = &Kch[l * KS];
            float l0[16], l1[16];
#pragma unroll
            for (int ll = 0; ll < 16; ++ll) { l0[ll] = 0.0f; l1[ll] = 0.0f; }
#pragma unroll
            for (int c = 0; c < DD; c += 4) {
                float4 kv = *(const float4*)&kb[c];
                float4 q0 = *(const float4*)&qa0[c];
                float4 q1 = *(const float4*)&qa1[c];
                int s = c & 15;
                l0[s + 0] = __fmaf_rn(q0.x, kv.x, l0[s + 0]);
                l0[s + 1] = __fmaf_rn(q0.y, kv.y, l0[s + 1]);
                l0[s + 2] = __fmaf_rn(q0.z, kv.z, l0[s + 2]);
                l0[s + 3] = __fmaf_rn(q0.w, kv.w, l0[s + 3]);
                l1[s + 0] = __fmaf_rn(q1.x, kv.x, l1[s + 0]);
                l1[s + 1] = __fmaf_rn(q1.y, kv.y, l1[s + 1]);
                l1[s + 2] = __fmaf_rn(q1.z, kv.z, l1[s + 2]);
                l1[s + 3] = __fmaf_rn(q1.w, kv.w, l1[s + 3]);
            }
            float e0 = reduce_np16(l0) / 8.0f;     // scale = sqrt(64), exact
            float e1 = reduce_np16(l1) / 8.0f;
            A[2 * rg + 0][j] = 1.0f / (1.0f + expf(-e0));  // sigmoid domain
            A[2 * rg + 1][j] = 1.0f / (1.0f + expf(-e1));
        }
    }

    const long long obase = (long long)(b * NN + row_base + wrow) * NN;

#pragma unroll
    for (int r = 0; r < 4; ++r) {
        float L[8];
#pragma unroll
        for (int j = 0; j < 8; ++j) L[j] = A[r][j];

        // Batcher odd-even merge sort, 8 elems, descending
        cxf(L[0],L[1]); cxf(L[2],L[3]); cxf(L[4],L[5]); cxf(L[6],L[7]);
        cxf(L[0],L[2]); cxf(L[1],L[3]); cxf(L[4],L[6]); cxf(L[5],L[7]);
        cxf(L[1],L[2]); cxf(L[5],L[6]);
        cxf(L[0],L[4]); cxf(L[1],L[5]); cxf(L[2],L[6]); cxf(L[3],L[7]);
        cxf(L[2],L[4]); cxf(L[3],L[5]);
        cxf(L[1],L[2]); cxf(L[3],L[4]); cxf(L[5],L[6]);

        // 64-lane butterfly merge: global top-8 of the row in every lane
#pragma unroll
        for (int mask = 1; mask < 64; mask <<= 1) {
            float Pr[8], M[8];
#pragma unroll
            for (int j = 0; j < 8; ++j) Pr[j] = __shfl_xor(L[j], mask, 64);
#pragma unroll
            for (int j = 0; j < 8; ++j) M[j] = fmaxf(L[j], Pr[7 - j]);
            cxf(M[0],M[4]); cxf(M[1],M[5]); cxf(M[2],M[6]); cxf(M[3],M[7]);
            cxf(M[0],M[2]); cxf(M[1],M[3]); cxf(M[4],M[6]); cxf(M[5],M[7]);
            cxf(M[0],M[1]); cxf(M[2],M[3]); cxf(M[4],M[5]); cxf(M[6],M[7]);
#pragma unroll
            for (int j = 0; j < 8; ++j) L[j] = M[j];
        }
        const float kth = L[7];

        float* orow = outp + obase + (long long)r * NN;
#pragma unroll
        for (int j = 0; j < 8; ++j)
            orow[(j << 6) + l] = (A[r][j] >= kth) ? A[r][j] : 0.0f;
    }
}

extern "C" void kernel_launch(void* const* d_in, const int* in_sizes, int n_in,
                              void* d_out, int out_size, void* d_ws, size_t ws_size,
                              hipStream_t stream) {
    const float* x     = (const float*)d_in[0];
    const float* Ws    = (const float*)d_in[1];
    const float* Wphi  = (const float*)d_in[2];
    const float* b_phi = (const float*)d_in[3];
    const float* Wmu   = (const float*)d_in[4];
    const float* b_mu  = (const float*)d_in[5];
    const float* WQ    = (const float*)d_in[6];
    const float* WK    = (const float*)d_in[7];
    float* out = (float*)d_out;

    // Q/K handoff in d_ws (8 MB); fully rewritten by k1 each call -> deterministic.
    float* gQ = (float*)d_ws;
    float* gK = gQ + (long long)BB * NN * DD;

    hipLaunchKernelGGL(k1, dim3(8192), dim3(256), 0, stream,
                       x, Ws, Wphi, b_phi, Wmu, b_mu, WQ, WK, gQ, gK);
    hipLaunchKernelGGL(k2f, dim3(1024), dim3(256), 0, stream, gQ, gK, out);
}